// Round 1
// 191.868 us; speedup vs baseline: 1.4791x; 1.4791x over previous
//
#include <hip/hip_runtime.h>
#include <hip/hip_bf16.h>
#include <math.h>

#define TS 16      // src rows per block (one 16-row MFMA tile, 4 waves split dst)
#define KNN 8
#define NB 8
#define SAP 68     // sA row stride (floats)

typedef short short8 __attribute__((ext_vector_type(8)));   // 8 bf16 (4 VGPRs)
typedef float f32x4  __attribute__((ext_vector_type(4)));
typedef unsigned long long u64;

__device__ __forceinline__ float bf2f(unsigned short b) {
  union { unsigned int i; float f; } t;
  t.i = ((unsigned int)b) << 16;
  return t.f;
}

__device__ __forceinline__ void bf8_to_f8(uint4 u, float* dst) {
  union { unsigned int i; float f; } t;
  t.i = u.x << 16;          dst[0] = t.f;
  t.i = u.x & 0xffff0000u;  dst[1] = t.f;
  t.i = u.y << 16;          dst[2] = t.f;
  t.i = u.y & 0xffff0000u;  dst[3] = t.f;
  t.i = u.z << 16;          dst[4] = t.f;
  t.i = u.z & 0xffff0000u;  dst[5] = t.f;
  t.i = u.w << 16;          dst[6] = t.f;
  t.i = u.w & 0xffff0000u;  dst[7] = t.f;
}

// load elems [c*8, c*8+8) of row r (64 elems/row) as f32
__device__ __forceinline__ void load8(const void* emb, int r, int c, int embf, float* v) {
  if (embf) {
    uint4 u = ((const uint4*)emb)[(size_t)r * 8 + c];
    bf8_to_f8(u, v);
  } else {
    float4 a = ((const float4*)emb)[(size_t)r * 16 + c * 2];
    float4 b = ((const float4*)emb)[(size_t)r * 16 + c * 2 + 1];
    v[0] = a.x; v[1] = a.y; v[2] = a.z; v[3] = a.w;
    v[4] = b.x; v[5] = b.y; v[6] = b.z; v[7] = b.w;
  }
}

__device__ __forceinline__ unsigned short f2bf(float f) {
  union { float f; unsigned u; } t; t.f = f;
  unsigned r = (t.u + 0x7FFFu + ((t.u >> 16) & 1u)) >> 16;
  return (unsigned short)r;
}

// MFMA A/B fragment: lane (m=lane&15, q=lane>>4) holds row elems [half*32+8q,+8)
__device__ __forceinline__ short8 ldfrag(const void* emb, int row, int q, int half, int embf) {
  if (embf) {
    union { uint4 u; short8 s; } t;
    t.u = ((const uint4*)emb)[(size_t)row * 8 + half * 4 + q];
    return t.s;
  } else {
    const float4* p = (const float4*)emb + (size_t)row * 16 + half * 8 + 2 * q;
    float4 x = p[0], y = p[1];
    short8 r;
    r[0] = (short)f2bf(x.x); r[1] = (short)f2bf(x.y);
    r[2] = (short)f2bf(x.z); r[3] = (short)f2bf(x.w);
    r[4] = (short)f2bf(y.x); r[5] = (short)f2bf(y.y);
    r[6] = (short)f2bf(y.z); r[7] = (short)f2bf(y.w);
    return r;
  }
}

// sum of squares of the 8 bf16 values in a fragment register (f32 exact)
__device__ __forceinline__ float sq8(short8 s) {
  float acc = 0.f;
  #pragma unroll
  for (int k = 0; k < 8; ++k) {
    union { unsigned u; float f; } t;
    t.u = ((unsigned)(unsigned short)s[k]) << 16;
    acc = fmaf(t.f, t.f, acc);
  }
  return acc;
}

// serial fma chain over 8 elems at offset o of row (bf16-rounded values) --
// bit-exact replica of sq8's per-fragment chain, for the norm precompute.
__device__ __forceinline__ float chain8x(const void* emb, int row, int o, int embf) {
  float acc = 0.f;
  if (embf) {
    const unsigned short* p = (const unsigned short*)emb + (size_t)row * 64 + o;
    #pragma unroll
    for (int k = 0; k < 8; ++k) {
      union { unsigned u; float f; } t;
      t.u = ((unsigned)p[k]) << 16;
      acc = fmaf(t.f, t.f, acc);
    }
  } else {
    const float* p = (const float*)emb + (size_t)row * 64 + o;
    #pragma unroll
    for (int k = 0; k < 8; ++k) {
      union { unsigned u; float f; } t;
      t.u = ((unsigned)f2bf(p[k])) << 16;
      acc = fmaf(t.f, t.f, acc);
    }
  }
  return acc;
}

// float -> order-preserving u32 (asc)
__device__ __forceinline__ unsigned f2ord(float f) {
  unsigned u = __float_as_uint(f);
  return u ^ (0x80000000u | (unsigned)((int)u >> 31));
}

// ---- numpy-f32 arithmetic replicas (exact final ordering) ----
__device__ __forceinline__ float np_sq64(const float* x) {
  float r0 = fmaf(x[0], x[0], 0.f), r1 = fmaf(x[1], x[1], 0.f);
  float r2 = fmaf(x[2], x[2], 0.f), r3 = fmaf(x[3], x[3], 0.f);
  float r4 = fmaf(x[4], x[4], 0.f), r5 = fmaf(x[5], x[5], 0.f);
  float r6 = fmaf(x[6], x[6], 0.f), r7 = fmaf(x[7], x[7], 0.f);
  #pragma unroll
  for (int u = 1; u < 8; ++u) {
    const float* p = x + 8 * u;
    r0 = r0 + fmaf(p[0], p[0], 0.f); r1 = r1 + fmaf(p[1], p[1], 0.f);
    r2 = r2 + fmaf(p[2], p[2], 0.f); r3 = r3 + fmaf(p[3], p[3], 0.f);
    r4 = r4 + fmaf(p[4], p[4], 0.f); r5 = r5 + fmaf(p[5], p[5], 0.f);
    r6 = r6 + fmaf(p[6], p[6], 0.f); r7 = r7 + fmaf(p[7], p[7], 0.f);
  }
  return ((r0 + r1) + (r2 + r3)) + ((r4 + r5) + (r6 + r7));
}

__device__ __forceinline__ float np_dot64(const float* a, const float* b) {
  float d = 0.f;
  #pragma unroll
  for (int k = 0; k < 64; ++k) d = fmaf(a[k], b[k], d);
  return d;
}

__device__ __forceinline__ float np_score(float ss, float dot, float sd) {
  float t = ss - 2.0f * dot;
  return t + sd;
}

// batch decode; mode: 0=int32, 1=int64(lo word), 2=bf16, 3=f32
__device__ __forceinline__ int batch_at(const void* p, int i, int mode) {
  if (mode == 0) return ((const int*)p)[i];
  if (mode == 1) return ((const int*)p)[2 * i];
  float v;
  if (mode == 2) v = bf2f(((const unsigned short*)p)[i]);
  else           v = ((const float*)p)[i];
  if (!(v >= -1e9f && v <= 1e9f)) return 999999;
  return (int)floorf(v + 0.5f);
}

__device__ __forceinline__ int lb_batch(const void* a, int n, int v, int mode) {
  int lo = 0, hi = n;
  while (lo < hi) { int m = (lo + hi) >> 1; if (batch_at(a, m, mode) < v) lo = m + 1; else hi = m; }
  return lo;
}

// ---- k_pre: block 0 = dtype detect + segment bounds + block map + zero stats.
//      blocks >= 1 (only when pre==1): bf16 conversion of src/dst into ws +
//      dst-norm precompute (bit-exact replica of the in-loop sq8+shfl sum). ----
__global__ __launch_bounds__(256) void k_pre(const void* __restrict__ src_emb,
                                             const void* __restrict__ dst_emb,
                                             const void* __restrict__ sb,
                                             const void* __restrict__ db,
                                             int* __restrict__ wsi,
                                             double* __restrict__ wsd,
                                             float* __restrict__ wsn,
                                             unsigned int* __restrict__ srcb,
                                             unsigned int* __restrict__ dstb,
                                             int n, int pre) {
  __shared__ int pv[2][4][18];
  __shared__ int pok[2][4];
  __shared__ int md[2];
  __shared__ int segs[18];
  __shared__ int embf_sh;
  const int tid = threadIdx.x;
  const unsigned short* src_bits = (const unsigned short*)src_emb;

  if (tid < 64) {
    unsigned short x = src_bits[tid];
    int e = (x >> 7) & 0xFF;
    bool okb = (x == 0) || ((e >= 0x60) && (e <= 0x9F));
    unsigned long long mb = __ballot(okb);
    if (tid == 0) embf_sh = (__popcll(mb) >= 56) ? 1 : 0;
  }
  if (blockIdx.x == 0) {
    if (tid >= 64 && tid < 136) {
      int t2 = tid - 64;
      int a = t2 / 36, m = (t2 % 36) / 9, j = t2 % 9;
      const void* p = a ? db : sb;
      long long span = (m == 1 || m == 3) ? (long long)((n - 2) / 2) : (long long)(n - 2);
      int e0 = (int)((span * j) / 8);
      pv[a][m][2 * j]     = batch_at(p, e0, m);
      pv[a][m][2 * j + 1] = batch_at(p, e0 + 1, m);
    }
  }
  __syncthreads();

  if (blockIdx.x > 0) {
    // conversion / norm blocks (launched only when pre==1)
    const int embf = embf_sh;
    const int cb = (int)blockIdx.x - 1;
    const int nbd = (n + 15) >> 4;
    if (cb < nbd) {
      const int r0 = cb << 4;
      if (!embf) {
        int row = r0 + (tid >> 4), c = tid & 15;
        if (row < n) {
          float4 x = ((const float4*)dst_emb)[(size_t)row * 16 + c];
          uint2 pp;
          pp.x = (unsigned)f2bf(x.x) | ((unsigned)f2bf(x.y) << 16);
          pp.y = (unsigned)f2bf(x.z) | ((unsigned)f2bf(x.w) << 16);
          ((uint2*)dstb)[(size_t)row * 16 + c] = pp;
        }
      }
      if (tid < 64) {
        // lane l: row r0 + l/4, part q = l&3; norm = (c0+c1)+(c2+c3),
        // cq = chain8(8q) + chain8(32+8q)  -- identical fp order to sq8+shfl.
        int row = r0 + (tid >> 2), qq = tid & 3;
        float cq = 0.f;
        if (row < n)
          cq = chain8x(dst_emb, row, 8 * qq, embf) + chain8x(dst_emb, row, 32 + 8 * qq, embf);
        float c01 = cq + __shfl_xor(cq, 1);
        float nrm = c01 + __shfl_xor(c01, 2);
        if (qq == 0 && row < n) wsn[row] = nrm;
      }
    } else {
      const int r0 = (cb - nbd) << 4;
      if (!embf) {
        int row = r0 + (tid >> 4), c = tid & 15;
        if (row < n) {
          float4 x = ((const float4*)src_emb)[(size_t)row * 16 + c];
          uint2 pp;
          pp.x = (unsigned)f2bf(x.x) | ((unsigned)f2bf(x.y) << 16);
          pp.y = (unsigned)f2bf(x.z) | ((unsigned)f2bf(x.w) << 16);
          ((uint2*)srcb)[(size_t)row * 16 + c] = pp;
        }
      }
    }
    return;
  }

  if (tid < 8) {
    int a = tid >> 2, m = tid & 3;
    int prev = -1, mx = 0; bool okv = true;
    for (int q = 0; q < 18; ++q) {
      int v = pv[a][m][q];
      if (v < 0 || v > 63 || v < prev) { okv = false; break; }
      prev = v; if (v > mx) mx = v;
    }
    pok[a][m] = (okv && mx >= 1) ? 1 : 0;
  }
  __syncthreads();
  if (tid < 2) {
    int a = tid, mm = 0;
    if      (pok[a][0]) mm = 0;
    else if (pok[a][1]) mm = 1;
    else if (pok[a][2]) mm = 2;
    else if (pok[a][3]) mm = 3;
    md[a] = mm;
  }
  __syncthreads();
  if (tid < 18) {
    int a = (tid < 9) ? 0 : 1;
    int bb = (tid < 9) ? tid : tid - 9;
    const void* p = a ? db : sb;
    segs[tid] = (bb == 0) ? 0 : ((bb == 8) ? n : lb_batch(p, n, bb, md[a]));
  }
  __syncthreads();
  if (tid == 0) {
    for (int h = 0; h < 2; ++h) {
      int off = h * 9;
      int prev = 0; segs[off] = 0;
      for (int i2 = 1; i2 < 8; ++i2) {
        int v = segs[off + i2];
        if (v < prev) v = prev; if (v > n) v = n;
        segs[off + i2] = v; prev = v;
      }
      segs[off + 8] = n;
    }
    for (int i2 = 0; i2 < 18; ++i2) wsi[i2] = segs[i2];
    wsi[18] = embf_sh;
    wsi[19] = pre;
    int c = 0; wsi[20] = 0;
    for (int bb = 0; bb < 8; ++bb) {
      c += (segs[bb + 1] - segs[bb] + TS - 1) / TS;
      wsi[21 + bb] = c;
    }
    wsi[29] = 0; wsi[30] = 0; wsi[31] = 0;
    wsd[0] = 0.0; wsd[1] = 0.0; wsd[2] = 0.0;
  }
}

// ---- k_main: 16-row tile, 4 waves scan quarters; u64-key top-8; (256,3) ----
__global__ __launch_bounds__(256, 3) void k_main(const void* __restrict__ src_emb,
                                                 const void* __restrict__ dst_emb,
                                                 float* __restrict__ out,
                                                 const int* __restrict__ wsi,
                                                 double* __restrict__ wsd,
                                                 const float* __restrict__ wsn,
                                                 const unsigned int* __restrict__ srcb,
                                                 const unsigned int* __restrict__ dstb,
                                                 int n) {
  __shared__ __align__(16) float sA[TS * SAP];   // src rows f32 (rescore)
  __shared__ int   cmi[TS * 32];                 // per-row: 4 waves x 8 candidate idx
  __shared__ float rs_sc[TS * 32];
  __shared__ float rs_dt[TS * 32];
  __shared__ double redb[32];
  __shared__ int shi[32];

  const int tid = threadIdx.x;
  if (tid < 32) shi[tid] = wsi[tid];
  __syncthreads();

  const int g = blockIdx.x;
  if (g >= shi[28]) return;
  int b = 0;
  while (g >= shi[21 + b]) b++;
  const int s0 = shi[b], s1 = shi[b + 1];
  const int d0 = shi[9 + b], d1 = shi[10 + b];
  const int embf = shi[18];
  const int pre  = shi[19];
  const int tile0 = (g - shi[20 + b]) * TS;
  const int scnt = s1 - s0, dcnt = d1 - d0;
  const int nsrc = min(TS, scnt - tile0);

  // fragment source: precomputed bf16 ws arrays when available (f32 input),
  // original arrays when input is already bf16 or no workspace.
  const int fbf = (pre || embf) ? 1 : 0;
  const void* fs = (pre && !embf) ? (const void*)srcb : src_emb;
  const void* fd = (pre && !embf) ? (const void*)dstb : dst_emb;

  // stage src rows f32 (16 rows x 8 chunks)
  if (tid < 128) {
    int r = tid >> 3, c = tid & 7;
    int gs = s0 + tile0 + r; if (gs > n - 1) gs = n - 1;
    float v[8];
    load8(src_emb, gs, c, embf, v);
    *(float4*)&sA[r * SAP + c * 8]     = *(float4*)v;
    *(float4*)&sA[r * SAP + c * 8 + 4] = *(float4*)(v + 4);
  }

  const int w = tid >> 6, lane = tid & 63;
  const int mn = lane & 15, q = lane >> 4;

  // A fragments (16 rows, same for all waves)
  int gsA = s0 + tile0 + mn; if (gsA > n - 1) gsA = n - 1;
  const short8 a0 = ldfrag(fs, gsA, q, 0, fbf);
  const short8 a1 = ldfrag(fs, gsA, q, 1, fbf);

  // per-lane top-8 keyed lists for 4 C-rows (u64 = sortable(score)<<32 | idx)
  u64 L[4][8];
  #pragma unroll
  for (int r = 0; r < 4; ++r)
    #pragma unroll
    for (int i = 0; i < 8; ++i) L[r][i] = ~0ull;

  const int qlen = (dcnt + 3) >> 2;
  const int c0 = w * qlen;
  const int c1 = min(dcnt, c0 + qlen);

  // software-pipelined scan: prefetch next iteration's fragments + norm
  short8 nb0 = {}, nb1 = {};
  float nsq = 0.f;
  if (c0 < c1) {
    int col = c0 + mn;
    int j = d0 + min(col, dcnt - 1);
    nb0 = ldfrag(fd, j, q, 0, fbf);
    nb1 = ldfrag(fd, j, q, 1, fbf);
    if (pre) nsq = wsn[j];
  }
  for (int jb = c0; jb < c1; jb += 16) {
    short8 b0 = nb0, b1 = nb1;
    float sqv = nsq;
    const int col = jb + mn;
    const bool valid = col < c1;
    const int jcur = d0 + min(col, dcnt - 1);
    const int jb2 = jb + 16;
    if (jb2 < c1) {
      int col2 = jb2 + mn;
      int j2 = d0 + min(col2, dcnt - 1);
      nb0 = ldfrag(fd, j2, q, 0, fbf);
      nb1 = ldfrag(fd, j2, q, 1, fbf);
      if (pre) nsq = wsn[j2];
    }
    if (!pre) {
      sqv = sq8(b0) + sq8(b1);
      sqv += __shfl_xor(sqv, 16);
      sqv += __shfl_xor(sqv, 32);
    }
    f32x4 acc = {0.f, 0.f, 0.f, 0.f};
    acc = __builtin_amdgcn_mfma_f32_16x16x32_bf16(a0, b0, acc, 0, 0, 0);
    acc = __builtin_amdgcn_mfma_f32_16x16x32_bf16(a1, b1, acc, 0, 0, 0);
    #pragma unroll
    for (int j4 = 0; j4 < 4; ++j4) {              // C row = 4q+j4, col = mn
      float sc = fmaf(-2.f, acc[j4], sqv);
      u64 key = ((u64)f2ord(sc) << 32) | (unsigned)jcur;
      if (valid && key < L[j4][7]) {
        u64 kk = key;
        #pragma unroll
        for (int p = 0; p < 8; ++p) {
          bool less = kk < L[j4][p];
          u64 tv = L[j4][p];
          if (less) { L[j4][p] = kk; kk = tv; }
        }
      }
    }
  }

  // per-wave 8-round shfl tournament: wave-top-8 per row -> LDS idx
  #pragma unroll
  for (int j4 = 0; j4 < 4; ++j4) {
    int myW = -1;
    #pragma unroll
    for (int rnd = 0; rnd < 8; ++rnd) {
      u64 bk = L[j4][0];
      u64 h0 = bk;
      #pragma unroll
      for (int m = 1; m < 16; m <<= 1) {
        u64 ok = __shfl_xor(bk, m);
        if (ok < bk) bk = ok;
      }
      bool won = (h0 == bk) && (h0 != ~0ull);
      #pragma unroll
      for (int p = 0; p < 7; ++p) L[j4][p] = won ? L[j4][p + 1] : L[j4][p];
      if (won) L[j4][7] = ~0ull;
      if (mn == rnd) myW = (bk == ~0ull) ? -1 : (int)(unsigned)(bk & 0xFFFFFFFFu);
    }
    if (mn < 8) cmi[(4 * q + j4) * 32 + w * 8 + mn] = myW;
  }
  __syncthreads();

  // np-f32 exact rescore: 512 candidates (16 rows x 32), 2 per thread
  #pragma unroll
  for (int half = 0; half < 2; ++half) {
    int item = tid + 256 * half;
    int r = item >> 5;
    int id = cmi[item];
    float sc = INFINITY, dt = 0.f;
    if (r < nsrc && id >= 0 && id < n) {
      float dreg[64];
      #pragma unroll
      for (int cc = 0; cc < 8; ++cc) load8(dst_emb, id, cc, embf, dreg + 8 * cc);
      const float* sp = &sA[r * SAP];
      float dot = np_dot64(sp, dreg);
      sc = np_score(np_sq64(sp), dot, np_sq64(dreg));
      dt = dot;
    }
    rs_sc[item] = sc;
    rs_dt[item] = dt;
  }
  __syncthreads();

  // parallel final top-8 per row: 16 threads/row, shfl-reduce per round.
  // key = ord(np_score)<<32 | idx  (idx unique across the 32 slots), so
  // ordering + tie-break (lower idx) matches the serial reference exactly.
  {
    const int r = tid >> 4, sub = tid & 15;
    const int base = r * 32;
    const int Mn = n * KNN;
    const int sg = s0 + tile0 + r;
    int idA = cmi[base + sub],       idB = cmi[base + 16 + sub];
    float scA = rs_sc[base + sub],   scB = rs_sc[base + 16 + sub];
    float dtA = rs_dt[base + sub],   dtB = rs_dt[base + 16 + sub];
    u64 kA = (idA >= 0 && idA < n) ? ((((u64)f2ord(scA)) << 32) | (unsigned)idA) : ~0ull;
    u64 kB = (idB >= 0 && idB < n) ? ((((u64)f2ord(scB)) << 32) | (unsigned)idB) : ~0ull;
    double lsum = 0.0, lsum2 = 0.0;
    #pragma unroll
    for (int rr = 0; rr < 8; ++rr) {
      u64 mk = kA; float mdt = dtA;
      if (kB < mk) { mk = kB; mdt = dtB; }
      #pragma unroll
      for (int m = 1; m < 16; m <<= 1) {
        u64 ok = __shfl_xor(mk, m);
        float od = __shfl_xor(mdt, m);
        if (ok < mk) { mk = ok; mdt = od; }
      }
      // retire winner from its owner lane (keys unique; ~0ull self-clear is harmless)
      if (mk == kA) kA = ~0ull;
      if (mk == kB) kB = ~0ull;
      bool have = (mk != ~0ull);
      float dv = have ? mdt : 0.f;
      if (r < nsrc && sub == rr) {
        int bidx = have ? (int)(unsigned)(mk & 0xFFFFFFFFu) : 0;
        size_t e = (size_t)sg * KNN + rr;
        out[e]          = (float)sg;
        out[Mn + e]     = (float)bidx;
        out[2 * Mn + e] = dv;               // lik stash (overwritten by k_s2)
      }
      if (sub == 0) { lsum += (double)dv; lsum2 += (double)dv * (double)dv; }
    }
    if (sub == 0) {
      redb[r]      = (r < nsrc) ? lsum  : 0.0;
      redb[16 + r] = (r < nsrc) ? lsum2 : 0.0;
    }
  }
  __syncthreads();
  if (tid == 0) {
    double a = 0.0, qq = 0.0;
    for (int i = 0; i < 16; ++i) { a += redb[i]; qq += redb[16 + i]; }
    atomicAdd(&wsd[0], a);
    atomicAdd(&wsd[1], qq);
  }
}

// ---- k_s2: BN + sigmoid; write w; accumulate sum(w) ----
__global__ __launch_bounds__(256) void k_s2(float* __restrict__ out,
                                            double* __restrict__ wsd,
                                            const void* __restrict__ gp,
                                            const void* __restrict__ bp, int M) {
  __shared__ double red[256];
  const int tid = threadIdx.x;
  double dM = (double)M;
  double mean = wsd[0] / dM;
  double var  = wsd[1] / dM - mean * mean;
  if (!(var >= 0.0)) var = 0.0;
  double inv = 1.0 / sqrt(var + 1e-5);
  unsigned short glo = ((const unsigned short*)gp)[0];
  int scbf = (glo != 0) ? 1 : 0;
  double g  = scbf ? (double)bf2f(glo) : (double)((const float*)gp)[0];
  unsigned short blo = ((const unsigned short*)bp)[0];
  double be = scbf ? (double)bf2f(blo) : (double)((const float*)bp)[0];

  float* lik = out + 2 * (size_t)M;
  const int chunk = (M + 127) / 128;
  const int i0 = blockIdx.x * chunk;
  const int i1 = min(i0 + chunk, M);
  double sw = 0.0;
  for (int i = i0 + tid; i < i1; i += 256) {
    double v = (double)lik[i];
    float z = (float)((v - mean) * inv * g + be);
    float wv = 1.0f / (1.0f + expf(-z));
    if (!isfinite(wv)) wv = 0.5f;
    lik[i] = wv;
    sw += (double)wv;
  }
  red[tid] = sw; __syncthreads();
  for (int st = 128; st > 0; st >>= 1) { if (tid < st) red[tid] += red[tid + st]; __syncthreads(); }
  if (tid == 0) atomicAdd(&wsd[2], red[0]);
}

// ---- k_s3: normalize w by mean(w) ----
__global__ __launch_bounds__(256) void k_s3(float* __restrict__ out,
                                            const double* __restrict__ wsd, int M) {
  double meanw = wsd[2] / (double)M;
  float* lik = out + 2 * (size_t)M;
  const int chunk = (M + 127) / 128;
  const int i0 = blockIdx.x * chunk;
  const int i1 = min(i0 + chunk, M);
  for (int i = i0 + threadIdx.x; i < i1; i += 256) {
    double wv = (double)lik[i];
    float r = (meanw > 0.0 && isfinite(meanw)) ? (float)(wv / meanw) : 1.0f;
    if (!isfinite(r)) r = 1.0f;
    lik[i] = r;
  }
}

extern "C" void kernel_launch(void* const* d_in, const int* in_sizes, int n_in,
                              void* d_out, int out_size, void* d_ws, size_t ws_size,
                              hipStream_t stream) {
  const void* src_emb = d_in[0];
  const void* dst_emb = d_in[1];
  const void* sb = d_in[2];
  const void* db = d_in[3];
  const void* gp = d_in[4];
  const void* bp = d_in[5];
  int n = in_sizes[0] / 64;
  const int M = n * KNN;

  float* out = (float*)d_out;
  int*    wsi = (int*)d_ws;
  double* wsd = (double*)((char*)d_ws + 192);

  // workspace layout for the precompute path:
  //   [512, 512+4n)          dst norms (f32)
  //   [off_d, off_d+128n)    dst bf16 (32 u32 per row)
  //   [off_s, off_s+128n)    src bf16
  size_t off_n = 512;
  size_t off_d = off_n + (((size_t)n * 4 + 15) & ~(size_t)15);
  size_t off_s = off_d + (size_t)n * 128;
  size_t need  = off_s + (size_t)n * 128;
  int pre = (ws_size >= need) ? 1 : 0;
  float*        wsn  = (float*)((char*)d_ws + off_n);
  unsigned int* dstb = (unsigned int*)((char*)d_ws + off_d);
  unsigned int* srcb = (unsigned int*)((char*)d_ws + off_s);

  int nbd = (n + 15) >> 4;
  int preg = pre ? (1 + 2 * nbd) : 1;

  k_pre<<<dim3(preg), dim3(256), 0, stream>>>(src_emb, dst_emb, sb, db, wsi, wsd,
                                              wsn, srcb, dstb, n, pre);
  k_main<<<dim3(n / TS + NB), dim3(256), 0, stream>>>(src_emb, dst_emb, out, wsi, wsd,
                                                      wsn, srcb, dstb, n);
  k_s2<<<dim3(128), dim3(256), 0, stream>>>(out, wsd, gp, bp, M);
  k_s3<<<dim3(128), dim3(256), 0, stream>>>(out, wsd, M);
}